// Round 7
// baseline (141.041 us; speedup 1.0000x reference)
//
#include <hip/hip_runtime.h>
#include <hip/hip_bf16.h>

#define B_N 4096
#define D_K 2048

typedef __attribute__((ext_vector_type(8))) short bf16x8;
typedef __attribute__((ext_vector_type(4))) float f32x4;

__device__ __forceinline__ unsigned short f2bf(float f) {
    union { __hip_bfloat16 h; unsigned short u; } cv;
    cv.h = __float2bfloat16(f);
    return cv.u;
}

__device__ __forceinline__ void gl_lds16(const unsigned short* g, unsigned short* l) {
    __builtin_amdgcn_global_load_lds(
        (const __attribute__((address_space(1))) unsigned int*)g,
        (__attribute__((address_space(3))) unsigned int*)l,
        16, 0, 0);
}

// ---------------- Kernel 1: row L2-normalize -> bf16 ----------------
__global__ __launch_bounds__(256) void knorm2(const float* __restrict__ C,
                                              const float* __restrict__ S,
                                              unsigned short* __restrict__ Cb,
                                              unsigned short* __restrict__ Sb) {
    int b = blockIdx.x;            // 0..8191
    const float* X;
    unsigned short* Y;
    if (b < B_N) { X = C + (size_t)b * D_K; Y = Cb + (size_t)b * D_K; }
    else         { X = S + (size_t)(b - B_N) * D_K; Y = Sb + (size_t)(b - B_N) * D_K; }
    int tid = threadIdx.x;

    float4 v0 = ((const float4*)X)[tid * 2];
    float4 v1 = ((const float4*)X)[tid * 2 + 1];
    float ss = v0.x*v0.x + v0.y*v0.y + v0.z*v0.z + v0.w*v0.w
             + v1.x*v1.x + v1.y*v1.y + v1.z*v1.z + v1.w*v1.w;
    #pragma unroll
    for (int off = 1; off < 64; off <<= 1) ss += __shfl_xor(ss, off, 64);
    __shared__ float wsum[4];
    if ((tid & 63) == 0) wsum[tid >> 6] = ss;
    __syncthreads();
    float tot = wsum[0] + wsum[1] + wsum[2] + wsum[3];
    float inv = 1.f / fmaxf(sqrtf(tot), 1e-12f);

    bf16x8 o;
    o[0] = (short)f2bf(v0.x * inv); o[1] = (short)f2bf(v0.y * inv);
    o[2] = (short)f2bf(v0.z * inv); o[3] = (short)f2bf(v0.w * inv);
    o[4] = (short)f2bf(v1.x * inv); o[5] = (short)f2bf(v1.y * inv);
    o[6] = (short)f2bf(v1.z * inv); o[7] = (short)f2bf(v1.w * inv);
    *(bf16x8*)(Y + tid * 8) = o;
}

// ---------------- Kernel 2: 256x256 read-early overlapped GEMM + fused InfoNCE epilogue ----------------
// Key change vs R6: every phase's ds_reads are issued BEFORE the PREVIOUS MFMA cluster
// completes issuing, so the LDS unit drains reads while the matrix pipe is busy.
//   P0: issue bO(t) reads   -> lgkm(4)  -> MMA Q00 (afA x bE[par])
//   P1: issue afB(t) reads  -> lgkm(8)  -> MMA Q01 (afA x bO)
//   P2: lgkm(0); BARRIER (c fully read) ; stage t+2 (8 gl_lds into c) -> MMA Q11 (afB x bO)
//   P3: vmcnt(8); BARRIER (cN=t+1 staged); issue bE[!par],afA (t+1) reads -> MMA Q10 (afB x bE[par])
// 2 barriers/tile, one vmcnt/tile, counted lgkm everywhere, B0-set parity-double-buffered (WAR).

#define BK 64
#define NT (D_K / BK)   /* 32 */

#define BARRIER()  asm volatile("s_barrier" ::: "memory")
#define LGKM(n)    asm volatile("s_waitcnt lgkmcnt(" #n ")" ::: "memory")
#define VMCNT(n)   asm volatile("s_waitcnt vmcnt(" #n ")" ::: "memory")
#define SCHEDB()   __builtin_amdgcn_sched_barrier(0)
#define PRIO1()    __builtin_amdgcn_s_setprio(1)
#define PRIO0()    __builtin_amdgcn_s_setprio(0)

#define LDA_(boff, qm, dst) do { _Pragma("unroll") \
  for (int mf = 0; mf < 4; ++mf) { \
    dst[mf][0] = *(const bf16x8*)(ldsb + (boff) + (qm)*16384 + abase + mf*2048 + c0); \
    dst[mf][1] = *(const bf16x8*)(ldsb + (boff) + (qm)*16384 + abase + mf*2048 + c1); \
  } } while (0)

#define LDB_(boff, p, dst) do { _Pragma("unroll") \
  for (int nf = 0; nf < 2; ++nf) { \
    dst[nf][0] = *(const bf16x8*)(ldsb + (boff) + 32768 + (p)*16384 + bbase + nf*2048 + c0); \
    dst[nf][1] = *(const bf16x8*)(ldsb + (boff) + 32768 + (p)*16384 + bbase + nf*2048 + c1); \
  } } while (0)

#define MMA_(qm, qn, aset, bset) do { _Pragma("unroll") \
  for (int mf = 0; mf < 4; ++mf) { _Pragma("unroll") \
    for (int nf = 0; nf < 2; ++nf) { \
      acc[(qm)*4+mf][(qn)*2+nf] = __builtin_amdgcn_mfma_f32_16x16x32_bf16(aset[mf][0], bset[nf][0], acc[(qm)*4+mf][(qn)*2+nf], 0, 0, 0); \
      acc[(qm)*4+mf][(qn)*2+nf] = __builtin_amdgcn_mfma_f32_16x16x32_bf16(aset[mf][1], bset[nf][1], acc[(qm)*4+mf][(qn)*2+nf], 0, 0, 0); \
    } } } while (0)

// A units: q=0 -> global rows {0..63}+{128..191}; q=1 -> {64..127}+{192..255}
#define STAGE_A_(boff, q, kk) do { \
  gl_lds16(gA + (size_t)((q) ?  64 : 0)   * D_K + (kk), (unsigned short*)(ldsb + (boff) + (q)*16384 +        tid*16)); \
  gl_lds16(gA + (size_t)((q) ? 192 : 128) * D_K + (kk), (unsigned short*)(ldsb + (boff) + (q)*16384 + 8192 + tid*16)); \
} while (0)

#define STAGE_B_(boff, p, kk) do { \
  gl_lds16(gB + (size_t)((p) ?  32 : 0)   * D_K + (kk), (unsigned short*)(ldsb + (boff) + 32768 + (p)*16384 +        tid*16)); \
  gl_lds16(gB + (size_t)((p) ? 160 : 128) * D_K + (kk), (unsigned short*)(ldsb + (boff) + 32768 + (p)*16384 + 8192 + tid*16)); \
} while (0)

// One K-tile = 4 phases. cc = this tile's buffer offset, cn = other buffer.
// bcur = B0 parity set for this tile, bnxt = set to preload for next tile.
// gS: stage tile tt+2 into cc at P2.  WV: vmcnt statement at P3 (or (void)0).
// gR: preload next tile's afA/bE at P3.
#define TILE4(cc, cn, bcur, bnxt, tt, gS, WV, gR) do { \
    /* P0: Q00 */ \
    LDB_(cc, 1, bO); \
    LGKM(4); SCHEDB(); \
    PRIO1(); MMA_(0, 0, afA, bcur); PRIO0(); \
    /* P1: Q01 */ \
    LDA_(cc, 1, afB); \
    LGKM(8); SCHEDB(); \
    PRIO1(); MMA_(0, 1, afA, bO); PRIO0(); \
    /* P2: Q11 */ \
    LGKM(0); \
    BARRIER(); \
    if (gS) { STAGE_A_(cc, 0, ((tt)+2)*BK); STAGE_A_(cc, 1, ((tt)+2)*BK); \
              STAGE_B_(cc, 0, ((tt)+2)*BK); STAGE_B_(cc, 1, ((tt)+2)*BK); } \
    SCHEDB(); \
    PRIO1(); MMA_(1, 1, afB, bO); PRIO0(); \
    /* P3: Q10 */ \
    WV; \
    BARRIER(); \
    if (gR) { LDB_(cn, 0, bnxt); LDA_(cn, 0, afA); } \
    SCHEDB(); \
    PRIO1(); MMA_(1, 0, afB, bcur); PRIO0(); \
} while (0)

__global__ __launch_bounds__(512, 2) void kgemm8(const unsigned short* __restrict__ Ab,
                                                 const unsigned short* __restrict__ Bb,
                                                 const float* __restrict__ temp,
                                                 float* __restrict__ rowsum,
                                                 float* __restrict__ colsum,
                                                 float* __restrict__ diag) {
    __shared__ __align__(128) char ldsb[131072];   // 128 KiB

    const int tid  = threadIdx.x;
    const int lane = tid & 63;
    const int wid  = tid >> 6;
    const int wm   = wid >> 2;     // 0..1
    const int wn   = wid & 3;      // 0..3

    // bijective XCD swizzle: 256 blocks = 8 XCDs x 32
    int bid = blockIdx.x;
    int swz = (bid & 7) * 32 + (bid >> 3);
    int brow = (swz >> 4) * 256;
    int bcol = (swz & 15) * 256;

    // ---- staging addresses: per-thread base + uniform row offsets ----
    const int rr = tid >> 3;                              // 0..63
    const int ch = (((tid & 7) ^ (rr & 7)) << 3);         // pre-swizzled k-chunk
    const unsigned short* gA = Ab + (size_t)(brow + rr) * D_K + ch;
    const unsigned short* gB = Bb + (size_t)(bcol + (rr >> 5) * 64 + (rr & 31)) * D_K + ch;

    // ---- ds_read constants (swizzled) ----
    const int lrow = lane & 15;
    const int kq   = lane >> 4;                 // 0..3
    const int sw   = (lane & 7) << 4;
    const int c0   = ((kq << 4)      ) ^ sw;
    const int c1   = (64 | (kq << 4)) ^ sw;
    const int abase = (wm * 64 + lrow) * 128;
    const int bbase = (wn * 32 + lrow) * 128;

    f32x4 acc[8][4];
    #pragma unroll
    for (int i = 0; i < 8; ++i)
        #pragma unroll
        for (int j = 0; j < 4; ++j) acc[i][j] = (f32x4){0.f, 0.f, 0.f, 0.f};
    bf16x8 afA[4][2];      // A0(t)
    bf16x8 afB[4][2];      // A1(t)
    bf16x8 bO[2][2];       // B1(t)
    bf16x8 bEa[2][2];      // B0(even tiles)
    bf16x8 bEb[2][2];      // B0(odd tiles)

    // ---- prologue: stage t0 -> buf0, t1 -> buf1; seed afA,bEa from buf0 ----
    STAGE_A_(0, 0, 0); STAGE_A_(0, 1, 0); STAGE_B_(0, 0, 0); STAGE_B_(0, 1, 0);
    STAGE_A_(65536, 0, BK); STAGE_A_(65536, 1, BK); STAGE_B_(65536, 0, BK); STAGE_B_(65536, 1, BK);
    VMCNT(8);              // t0's 8 loads complete; t1's 8 in flight
    BARRIER();
    LDB_(0, 0, bEa);       // B0(0) -> bEa (4 reads)
    LDA_(0, 0, afA);       // A0(0) -> afA (8 reads)

    #pragma unroll 1
    for (int t = 0; t < NT - 2; t += 2) {
        TILE4(0,     65536, bEa, bEb, t,     1, VMCNT(8), 1);
        TILE4(65536, 0,     bEb, bEa, t + 1, 1, VMCNT(8), 1);
    }
    // tail pair: no staging beyond K; last vmcnt must drain (younger batch absent)
    TILE4(0,     65536, bEa, bEb, NT - 2, 0, VMCNT(0), 1);
    TILE4(65536, 0,     bEb, bEa, NT - 1, 0, (void)0,  0);

    // ------- epilogue: relu*e^t, shifted exp, row/col partial sums, diag -------
    const float scl = expf(temp[0]);
    float cs[4] = {0.f, 0.f, 0.f, 0.f};
    #pragma unroll
    for (int mi = 0; mi < 8; ++mi) {
        float rs[4] = {0.f, 0.f, 0.f, 0.f};
        const int growb = brow + wm * 128 + (mi >> 2) * 64 + (mi & 3) * 16 + kq * 4;
        #pragma unroll
        for (int ni = 0; ni < 4; ++ni) {
            const int gc = bcol + wn * 64 + (ni >> 1) * 32 + (ni & 1) * 16 + lrow;
            #pragma unroll
            for (int j = 0; j < 4; ++j) {
                float v = fmaxf(acc[mi][ni][j], 0.f) * scl;
                if (growb + j == gc) diag[gc] = v;
                float p = expf(v - scl);
                rs[j]  += p;
                cs[ni] += p;
            }
        }
        #pragma unroll
        for (int j = 0; j < 4; ++j) {
            float v = rs[j];
            v += __shfl_xor(v, 1, 64);
            v += __shfl_xor(v, 2, 64);
            v += __shfl_xor(v, 4, 64);
            v += __shfl_xor(v, 8, 64);
            if (lrow == 0) atomicAdd(&rowsum[growb + j], v);
        }
    }
    #pragma unroll
    for (int ni = 0; ni < 4; ++ni) {
        float v = cs[ni];
        v += __shfl_xor(v, 16, 64);
        v += __shfl_xor(v, 32, 64);
        if (kq == 0) atomicAdd(&colsum[bcol + wn * 64 + (ni >> 1) * 32 + (ni & 1) * 16 + lrow], v);
    }
}

// ---------------- Kernel 3: final reduction to scalar loss ----------------
__global__ __launch_bounds__(256) void kfinal(const float* __restrict__ rowsum,
                                              const float* __restrict__ colsum,
                                              const float* __restrict__ diag,
                                              const float* __restrict__ temp,
                                              float* __restrict__ out) {
    int tid = threadIdx.x;
    float M = expf(temp[0]);
    float acc = 0.f;
    for (int i = tid; i < B_N; i += 256) {
        acc += logf(rowsum[i]) + logf(colsum[i]) + 2.f * M - 2.f * diag[i];
    }
    #pragma unroll
    for (int off = 1; off < 64; off <<= 1) acc += __shfl_xor(acc, off, 64);
    __shared__ float wsum[4];
    if ((tid & 63) == 0) wsum[tid >> 6] = acc;
    __syncthreads();
    if (tid == 0) {
        float t = wsum[0] + wsum[1] + wsum[2] + wsum[3];
        out[0] = t * (0.5f / (float)B_N);
    }
}

extern "C" void kernel_launch(void* const* d_in, const int* in_sizes, int n_in,
                              void* d_out, int out_size, void* d_ws, size_t ws_size,
                              hipStream_t stream) {
    const float* Cf   = (const float*)d_in[0];
    const float* Sf   = (const float*)d_in[1];
    const float* temp = (const float*)d_in[2];

    const size_t MATEL = (size_t)B_N * D_K;
    unsigned short* Cb = (unsigned short*)d_ws;            // 16 MB
    unsigned short* Sb = Cb + MATEL;                       // 16 MB
    float* rowsum = (float*)(Sb + MATEL);                  // 16 KB
    float* colsum = rowsum + B_N;
    float* diag   = colsum + B_N;

    hipMemsetAsync(rowsum, 0, 2 * B_N * sizeof(float), stream);
    knorm2<<<2 * B_N, 256, 0, stream>>>(Cf, Sf, Cb, Sb);
    kgemm8<<<256, 512, 0, stream>>>(Cb, Sb, temp, rowsum, colsum, diag);
    kfinal<<<1, 256, 0, stream>>>(rowsum, colsum, diag, temp, (float*)d_out);
}